// Round 9
// baseline (155.622 us; speedup 1.0000x reference)
//
#include <hip/hip_runtime.h>
#include <math.h>

#define N_NODES 16384
#define D_MODEL 256
#define H_HEADS 4
#define C_CH 256
#define E_EDGES 65536
#define ETOT (E_EDGES + N_NODES)
#define HC 1024
#define MAXDEG 64
#define PSZ 262144   // 256*1024 elements per partial buffer

typedef __bf16 bf16x8 __attribute__((ext_vector_type(8)));
typedef __bf16 bf16x4 __attribute__((ext_vector_type(4)));
typedef float f32x4 __attribute__((ext_vector_type(4)));

__device__ __forceinline__ __bf16 f2bf(float f) { return (__bf16)f; }
__device__ __forceinline__ float bf2f(__bf16 b) { return (float)b; }

// ==== K1: 0..63 t-partials | 64..1087 V-compose split-4 (64-iter chains) |
//          1088..1407 padded-CSR scatter | 1408..5503 LayerNorm ====
__global__ __launch_bounds__(256) void prep1_ln(
    const float* __restrict__ Wg, const float* __restrict__ att_src,
    const float* __restrict__ att_dst, const float* __restrict__ W2,
    const int* __restrict__ ei, const float* __restrict__ in,
    const float* __restrict__ gamma, const float* __restrict__ beta,
    float* __restrict__ t, float* __restrict__ Vp, int* __restrict__ cnt,
    int* __restrict__ csr, __bf16* __restrict__ x_ln)
{
    int b = blockIdx.x;
    int tid = threadIdx.x;
    if (b >= 1408) {
        int wave = tid >> 6, lane = tid & 63;
        int row = (b - 1408) * 4 + wave;
        float4 v = ((const float4*)(in + (size_t)row * D_MODEL))[lane];
        float s  = v.x + v.y + v.z + v.w;
        float sq = v.x*v.x + v.y*v.y + v.z*v.z + v.w*v.w;
        for (int off = 32; off; off >>= 1) {
            s  += __shfl_xor(s,  off);
            sq += __shfl_xor(sq, off);
        }
        float mean = s * (1.0f / D_MODEL);
        float var  = sq * (1.0f / D_MODEL) - mean * mean;
        float inv  = rsqrtf(var + 1e-6f);
        float4 g = ((const float4*)gamma)[lane];
        float4 bb = ((const float4*)beta)[lane];
        bf16x4 o;
        o[0] = f2bf((v.x - mean) * inv * g.x + bb.x);
        o[1] = f2bf((v.y - mean) * inv * g.y + bb.y);
        o[2] = f2bf((v.z - mean) * inv * g.z + bb.z);
        o[3] = f2bf((v.w - mean) * inv * g.w + bb.w);
        *(bf16x4*)(x_ln + (size_t)row * D_MODEL + lane * 4) = o;
        return;
    }
    if (b < 64) {
        int v = b >> 3, sl = b & 7, h = v & 3;
        const float* att = ((v < 4) ? att_src : att_dst) + h * C_CH;
        float acc = 0.f;
        #pragma unroll
        for (int j = 0; j < 32; ++j) {
            int c = sl * 32 + j;
            acc = fmaf(Wg[(size_t)(h * 256 + c) * 256 + tid], att[c], acc);
        }
        atomicAdd(&t[v * 256 + tid], acc);
        return;
    }
    if (b < 1088) {
        // V partial over one 64-wide c-slice, written to Vp[cs]
        int bb2 = b - 64;
        int orig = bb2 >> 2, cs = bb2 & 3;
        int og = (orig & 63) * 4, h = orig >> 6;
        const float* w2r = W2 + (size_t)og * 256;
        const float* wgp = Wg + ((size_t)h * 256) * 256 + tid;
        float a0 = 0.f, a1 = 0.f, a2 = 0.f, a3 = 0.f;
        int cb = cs * 64;
        #pragma unroll 4
        for (int c = cb; c < cb + 64; ++c) {
            float wv = wgp[(size_t)c * 256];
            a0 = fmaf(w2r[c],       wv, a0);
            a1 = fmaf(w2r[256 + c], wv, a1);
            a2 = fmaf(w2r[512 + c], wv, a2);
            a3 = fmaf(w2r[768 + c], wv, a3);
        }
        size_t base = (size_t)cs * PSZ + (size_t)og * 1024 + h * 256 + tid;
        Vp[base]        = a0;
        Vp[base + 1024] = a1;
        Vp[base + 2048] = a2;
        Vp[base + 3072] = a3;
        return;
    }
    {
        // padded-CSR scatter
        int e = (b - 1088) * 256 + tid;
        int src, dst;
        if (e < E_EDGES) { src = ei[e]; dst = ei[E_EDGES + e]; }
        else             { src = dst = e - E_EDGES; }
        int pos = atomicAdd(cnt + dst, 1);
        csr[(size_t)dst * MAXDEG + pos] = src;
    }
}

// ==== K2: 0..1023 Wz split-4 -> Wzp (plain stores; V summed from Vp via LDS) |
//          1024..1087 u2/c0 ====
__global__ __launch_bounds__(256) void prep2(
    const float* __restrict__ t, const float* __restrict__ W1,
    const float* __restrict__ b1, const float* __restrict__ Vp,
    const float* __restrict__ W2, const float* __restrict__ bg,
    const float* __restrict__ b2, float* __restrict__ u2,
    float* __restrict__ c0, float* __restrict__ Wzp,
    float* __restrict__ bias_z)
{
    __shared__ float red[4][4];
    __shared__ float vsh[4][64];
    int b = blockIdx.x;
    int d = threadIdx.x;

    if (b < 1024) {
        int orig = b >> 2, ks = b & 3;
        int og = (orig & 63) * 4, h = orig >> 6;
        int lane = d & 63, wid = d >> 6;
        int kb = ks * 64;
        size_t vbase = (size_t)og * 1024 + h * 256;

        // cooperative sum of the 4 V-partials for this block's 4x64 slice
        {
            int j = d >> 6, kk = d & 63;
            float s = 0.f;
            #pragma unroll
            for (int cs = 0; cs < 4; ++cs)
                s += Vp[(size_t)cs * PSZ + vbase + (size_t)j * 1024 + kb + kk];
            vsh[j][kk] = s;
        }
        __syncthreads();

        float a0 = 0.f, a1 = 0.f, a2 = 0.f, a3 = 0.f;
        #pragma unroll 4
        for (int k = 0; k < 64; ++k) {
            float w1v = W1[(size_t)(kb + k) * 256 + d];
            a0 = fmaf(vsh[0][k], w1v, a0);
            a1 = fmaf(vsh[1][k], w1v, a1);
            a2 = fmaf(vsh[2][k], w1v, a2);
            a3 = fmaf(vsh[3][k], w1v, a3);
        }
        size_t base = (size_t)ks * PSZ + vbase + d;
        Wzp[base]        = a0;
        Wzp[base + 1024] = a1;
        Wzp[base + 2048] = a2;
        Wzp[base + 3072] = a3;

        if (ks == 0) {
            float b1v = b1[d];
            #pragma unroll
            for (int j = 0; j < 4; ++j) {
                float vsum = 0.f;
                #pragma unroll
                for (int cs = 0; cs < 4; ++cs)
                    vsum += Vp[(size_t)cs * PSZ + vbase + (size_t)j * 1024 + d];
                float p = vsum * b1v;
                for (int s = 32; s; s >>= 1) p += __shfl_xor(p, s);
                if (lane == 0) red[j][wid] = p;
            }
            __syncthreads();
            if (d < 4) {
                float s = red[d][0] + red[d][1] + red[d][2] + red[d][3];
                atomicAdd(&bias_z[og + d], 0.25f * s);
            }
            if (h == 0) {
                __syncthreads();
                float bgv = bg[d];
                #pragma unroll
                for (int j = 0; j < 4; ++j) {
                    float q = W2[(size_t)(og + j) * 256 + d] * bgv;
                    for (int s = 32; s; s >>= 1) q += __shfl_xor(q, s);
                    if (lane == 0) red[j][wid] = q;
                }
                __syncthreads();
                if (d < 4) {
                    float s = red[d][0] + red[d][1] + red[d][2] + red[d][3];
                    atomicAdd(&bias_z[og + d], s + b2[og + d]);
                }
            }
        }
        return;
    }
    {
        int bb = b - 1024;
        int v = bb >> 3, sl = bb & 7;
        const float* tv = t + v * 256;
        float acc = 0.f;
        #pragma unroll
        for (int j = 0; j < 32; ++j) {
            int k = sl * 32 + j;
            acc = fmaf(tv[k], W1[(size_t)k * 256 + d], acc);
        }
        atomicAdd(&u2[v * 256 + d], acc);
        if (d < 32) {
            float p = tv[sl * 32 + d] * b1[sl * 32 + d];
            for (int s = 16; s; s >>= 1) p += __shfl_xor(p, s);
            if (d == 0) atomicAdd(&c0[v], p);
        }
    }
}

// ==== K3: 0..4095 logits | 4096..4351 Wzp sum + f32->bf16 cvt ====
__global__ __launch_bounds__(256) void logits_cvt(
    const __bf16* __restrict__ x_ln, const float* __restrict__ u2,
    const float* __restrict__ c0, float* __restrict__ a_src,
    float* __restrict__ a_dst, const float* __restrict__ Wzp,
    __bf16* __restrict__ Wz)
{
    int b = blockIdx.x;
    int tid = threadIdx.x;
    if (b >= 4096) {
        int idx = (b - 4096) * 256 + tid;    // 65536 float4 groups
        float4 v = make_float4(0.f, 0.f, 0.f, 0.f);
        #pragma unroll
        for (int p = 0; p < 4; ++p) {
            float4 t4 = ((const float4*)(Wzp + (size_t)p * PSZ))[idx];
            v.x += t4.x; v.y += t4.y; v.z += t4.z; v.w += t4.w;
        }
        bf16x4 o;
        o[0] = f2bf(v.x); o[1] = f2bf(v.y); o[2] = f2bf(v.z); o[3] = f2bf(v.w);
        *(bf16x4*)(Wz + (size_t)idx * 4) = o;
        return;
    }
    __shared__ float u2s[8][256];
    __shared__ float c0s[8];
    #pragma unroll
    for (int k = 0; k < 8; ++k) u2s[k][tid] = u2[k * 256 + tid];
    if (tid < 8) c0s[tid] = c0[tid];
    __syncthreads();

    int wave = tid >> 6, lane = tid & 63;
    int n = b * 4 + wave;
    int v = lane >> 3, p = lane & 7;
    const __bf16* xp = x_ln + (size_t)n * D_MODEL + p * 32;
    const float*  up = &u2s[v][p * 32];
    float acc = 0.f;
    #pragma unroll
    for (int ti = 0; ti < 4; ++ti) {
        bf16x8 x = *(const bf16x8*)(xp + ti * 8);
        #pragma unroll
        for (int j = 0; j < 8; ++j)
            acc = fmaf(bf2f(x[j]), up[ti * 8 + j], acc);
    }
    acc += __shfl_xor(acc, 1);
    acc += __shfl_xor(acc, 2);
    acc += __shfl_xor(acc, 4);
    if (p == 0) {
        float o = acc + c0s[v];
        if (v < 4) a_src[n * H_HEADS + v] = o;
        else       a_dst[n * H_HEADS + (v - 4)] = o;
    }
}

// ==== K4: fused softmax + aggregation, latency-parallel form ====
// Lane e owns edge e: all edge weights (a_src gather + leaky + exp) computed in
// parallel, off the serial path; softmax denom via wave-reduce; weights parked
// in LDS. The accumulation loop gathers x_ln rows in chunks of 8 INDEPENDENT
// loads (clamped-safe indices, weight=0 for invalid) — one latency exposure per
// 8 edges instead of one per edge (avg deg = 5).
__global__ __launch_bounds__(256) void gat_fused(
    const __bf16* __restrict__ x_ln, const float* __restrict__ a_src,
    const float* __restrict__ a_dst, const int* __restrict__ cnt,
    const int* __restrict__ csr, __bf16* __restrict__ agg)
{
    __shared__ float wsh[4][MAXDEG][4];
    int wave = threadIdx.x >> 6, lane = threadIdx.x & 63;
    int i = blockIdx.x * 4 + wave;
    int deg = cnt[i];
    int sidx = csr[(size_t)i * MAXDEG + lane];   // coalesced; garbage past deg
    float4 ad = *(const float4*)(a_dst + i * H_HEADS);

    // per-lane edge weight (lane = edge index)
    float4 wgt = make_float4(0.f, 0.f, 0.f, 0.f);
    if (lane < deg) {
        float4 as = *(const float4*)(a_src + sidx * H_HEADS);
        float l0 = as.x + ad.x, l1 = as.y + ad.y,
              l2 = as.z + ad.z, l3 = as.w + ad.w;
        l0 = (l0 > 0.f) ? l0 : 0.2f * l0;
        l1 = (l1 > 0.f) ? l1 : 0.2f * l1;
        l2 = (l2 > 0.f) ? l2 : 0.2f * l2;
        l3 = (l3 > 0.f) ? l3 : 0.2f * l3;
        wgt = make_float4(__expf(l0), __expf(l1), __expf(l2), __expf(l3));
    }
    // softmax denominators (invalid lanes contribute 0)
    float s0 = wgt.x, s1 = wgt.y, s2 = wgt.z, s3 = wgt.w;
    #pragma unroll
    for (int off = 32; off; off >>= 1) {
        s0 += __shfl_xor(s0, off);
        s1 += __shfl_xor(s1, off);
        s2 += __shfl_xor(s2, off);
        s3 += __shfl_xor(s3, off);
    }
    *(float4*)&wsh[wave][lane][0] = wgt;   // same-wave write->read, no barrier

    float acc[4][4] = {};
    for (int e0 = 0; e0 < deg; e0 += 8) {
        bf16x4 X[8];
        float4 W[8];
        #pragma unroll
        for (int j = 0; j < 8; ++j) {
            int ee = e0 + j;
            bool val = ee < deg;
            int el = val ? ee : 0;
            int s = __shfl(sidx, el);
            X[j] = *(const bf16x4*)(x_ln + (size_t)s * D_MODEL + lane * 4);
            float4 wv = *(const float4*)&wsh[wave][el][0];
            W[j] = val ? wv : make_float4(0.f, 0.f, 0.f, 0.f);
        }
        #pragma unroll
        for (int j = 0; j < 8; ++j) {
            #pragma unroll
            for (int d = 0; d < 4; ++d) {
                float xv = bf2f(X[j][d]);
                acc[0][d] = fmaf(W[j].x, xv, acc[0][d]);
                acc[1][d] = fmaf(W[j].y, xv, acc[1][d]);
                acc[2][d] = fmaf(W[j].z, xv, acc[2][d]);
                acc[3][d] = fmaf(W[j].w, xv, acc[3][d]);
            }
        }
    }
    float sc[4] = {0.25f / s0, 0.25f / s1, 0.25f / s2, 0.25f / s3};
    #pragma unroll
    for (int h = 0; h < 4; ++h) {
        bf16x4 o;
        #pragma unroll
        for (int j = 0; j < 4; ++j) o[j] = f2bf(acc[h][j] * sc[h]);
        *(bf16x4*)(agg + (size_t)i * HC + h * 256 + lane * 4) = o;
    }
}

// -------- K5: skinny bf16 GEMM, 512 threads / 8 waves per block --------
#define APAD 72

__global__ __launch_bounds__(512) void gemm_skinny(
    const __bf16* __restrict__ A, const __bf16* __restrict__ B,
    const float* __restrict__ bias, const float* __restrict__ resid,
    float* __restrict__ outf, int K)
{
    __shared__ __align__(16) __bf16 As[64 * APAD];
    __shared__ __align__(16) __bf16 Bs[256 * APAD];
    int tid  = threadIdx.x;
    int lane = tid & 63;
    int w    = tid >> 6;          // 0..7
    int quad = lane >> 4;
    int l16  = lane & 15;
    int m0 = blockIdx.x * 64;
    int n0 = w * 32;

    int srow = tid >> 3, sp = tid & 7;   // srow 0..63, sp 0..7
    const __bf16* Ab = A + (size_t)(m0 + srow) * K + sp * 8;
    const __bf16* Bb = B + (size_t)srow * K + sp * 8;
    size_t rstride = (size_t)64 * K;

    f32x4 acc[4][2] = {};

    bf16x8 a0_, b0_[4];
    bf16x8 a1_, b1_[4];

    auto compute = [&]() {
        #pragma unroll
        for (int ks = 0; ks < 2; ++ks) {
            bf16x8 af[4], bfr[2];
            #pragma unroll
            for (int mt = 0; mt < 4; ++mt)
                af[mt] = *(const bf16x8*)(As + (mt * 16 + l16) * APAD
                                          + ks * 32 + quad * 8);
            #pragma unroll
            for (int nt = 0; nt < 2; ++nt)
                bfr[nt] = *(const bf16x8*)(Bs + (n0 + nt * 16 + l16) * APAD
                                           + ks * 32 + quad * 8);
            #pragma unroll
            for (int mt = 0; mt < 4; ++mt)
                #pragma unroll
                for (int nt = 0; nt < 2; ++nt)
                    acc[mt][nt] = __builtin_amdgcn_mfma_f32_16x16x32_bf16(
                        af[mt], bfr[nt], acc[mt][nt], 0, 0, 0);
        }
    };

    a0_ = *(const bf16x8*)(Ab);
    #pragma unroll
    for (int t = 0; t < 4; ++t)
        b0_[t] = *(const bf16x8*)(Bb + t * rstride);

    for (int kb = 0; kb < K; kb += 128) {
        {
            const __bf16* Ap = Ab + kb + 64;
            const __bf16* Bp = Bb + kb + 64;
            a1_ = *(const bf16x8*)(Ap);
            #pragma unroll
            for (int t = 0; t < 4; ++t)
                b1_[t] = *(const bf16x8*)(Bp + t * rstride);
        }
        __syncthreads();
        *(bf16x8*)(As + srow * APAD + sp * 8) = a0_;
        #pragma unroll
        for (int t = 0; t < 4; ++t)
            *(bf16x8*)(Bs + (srow + t * 64) * APAD + sp * 8) = b0_[t];
        __syncthreads();
        compute();

        if (kb + 128 < K) {
            const __bf16* Ap = Ab + kb + 128;
            const __bf16* Bp = Bb + kb + 128;
            a0_ = *(const bf16x8*)(Ap);
            #pragma unroll
            for (int t = 0; t < 4; ++t)
                b0_[t] = *(const bf16x8*)(Bp + t * rstride);
        }
        __syncthreads();
        *(bf16x8*)(As + srow * APAD + sp * 8) = a1_;
        #pragma unroll
        for (int t = 0; t < 4; ++t)
            *(bf16x8*)(Bs + (srow + t * 64) * APAD + sp * 8) = b1_[t];
        __syncthreads();
        compute();
    }

    #pragma unroll
    for (int nt = 0; nt < 2; ++nt) {
        int col = n0 + nt * 16 + l16;
        float bv = bias[col];
        #pragma unroll
        for (int mt = 0; mt < 4; ++mt) {
            int row = m0 + mt * 16 + quad * 4;
            #pragma unroll
            for (int r = 0; r < 4; ++r) {
                size_t off = (size_t)(row + r) * C_CH + col;
                outf[off] = acc[mt][nt][r] + bv + resid[off];
            }
        }
    }
}

extern "C" void kernel_launch(void* const* d_in, const int* in_sizes, int n_in,
                              void* d_out, int out_size, void* d_ws, size_t ws_size,
                              hipStream_t stream)
{
    const float* inp      = (const float*)d_in[0];
    const int*   ei       = (const int*)  d_in[1];
    const float* ln_gamma = (const float*)d_in[2];
    const float* ln_beta  = (const float*)d_in[3];
    const float* W1       = (const float*)d_in[4];
    const float* b1       = (const float*)d_in[5];
    const float* W_gat    = (const float*)d_in[6];
    const float* att_src  = (const float*)d_in[7];
    const float* att_dst  = (const float*)d_in[8];
    const float* bias_gat = (const float*)d_in[9];
    const float* W2       = (const float*)d_in[10];
    const float* b2       = (const float*)d_in[11];

    char* ws = (char*)d_ws;
    __bf16* x_ln_bf = (__bf16*)(ws);                         //  8 MB
    __bf16* agg_bf  = (__bf16*)(ws + (8ull  << 20));         // 32 MB
    __bf16* Wz_b    = (__bf16*)(ws + (40ull << 20));         // 512 KB
    float*  a_src_b = (float*)(ws + (41ull << 20));          // 256 KB
    float*  a_dst_b = a_src_b + (size_t)N_NODES * H_HEADS;   // 256 KB
    // ---- zero region start (42 MB) ----
    float*  t_vec   = (float*)(ws + (42ull << 20));          //  8 KB
    float*  u2      = t_vec + 2048;                          //  8 KB
    float*  c0      = u2 + 2048;                             //  32 B
    float*  bias_z  = c0 + 8;                                //  1 KB
    int*    cnt     = (int*)(bias_z + 256);                  // 64 KB
    // ---- zero region end ----
    int*    csr     = (int*)(ws + (45ull << 20));            //  4 MB
    float*  Vp      = (float*)(ws + (49ull << 20));          //  4 MB (4 partials)
    float*  Wzp     = (float*)(ws + (57ull << 20));          //  4 MB (4 partials)

    size_t zbytes = (2048 + 2048 + 8 + 256) * sizeof(float)
                  + N_NODES * sizeof(int);
    hipMemsetAsync(t_vec, 0, zbytes, stream);

    prep1_ln<<<1408 + 4096, 256, 0, stream>>>(W_gat, att_src, att_dst, W2, ei,
                                              inp, ln_gamma, ln_beta,
                                              t_vec, Vp, cnt, csr, x_ln_bf);
    prep2<<<1088, 256, 0, stream>>>(t_vec, W1, b1, Vp, W2, bias_gat, b2,
                                    u2, c0, Wzp, bias_z);
    logits_cvt<<<4096 + 256, 256, 0, stream>>>(x_ln_bf, u2, c0,
                                               a_src_b, a_dst_b, Wzp, Wz_b);
    gat_fused<<<N_NODES / 4, 256, 0, stream>>>(x_ln_bf, a_src_b, a_dst_b,
                                               cnt, csr, agg_bf);
    gemm_skinny<<<N_NODES / 64, 512, 0, stream>>>(agg_bf, Wz_b, bias_z, inp,
                                                  (float*)d_out, HC);
}

// Round 10
// 154.497 us; speedup vs baseline: 1.0073x; 1.0073x over previous
//
#include <hip/hip_runtime.h>
#include <math.h>

#define N_NODES 16384
#define D_MODEL 256
#define H_HEADS 4
#define C_CH 256
#define E_EDGES 65536
#define ETOT (E_EDGES + N_NODES)
#define HC 1024
#define MAXDEG 64
#define PSZ 262144   // 256*1024 elements per partial buffer

typedef __bf16 bf16x8 __attribute__((ext_vector_type(8)));
typedef __bf16 bf16x4 __attribute__((ext_vector_type(4)));
typedef float f32x4 __attribute__((ext_vector_type(4)));

__device__ __forceinline__ __bf16 f2bf(float f) { return (__bf16)f; }
__device__ __forceinline__ float bf2f(__bf16 b) { return (float)b; }

// ==== K1: 0..63 t-partials | 64..1087 V-compose split-4 (64-iter chains) |
//          1088..1407 padded-CSR scatter | 1408..5503 LayerNorm ====
__global__ __launch_bounds__(256) void prep1_ln(
    const float* __restrict__ Wg, const float* __restrict__ att_src,
    const float* __restrict__ att_dst, const float* __restrict__ W2,
    const int* __restrict__ ei, const float* __restrict__ in,
    const float* __restrict__ gamma, const float* __restrict__ beta,
    float* __restrict__ t, float* __restrict__ Vp, int* __restrict__ cnt,
    int* __restrict__ csr, __bf16* __restrict__ x_ln)
{
    int b = blockIdx.x;
    int tid = threadIdx.x;
    if (b >= 1408) {
        int wave = tid >> 6, lane = tid & 63;
        int row = (b - 1408) * 4 + wave;
        float4 v = ((const float4*)(in + (size_t)row * D_MODEL))[lane];
        float s  = v.x + v.y + v.z + v.w;
        float sq = v.x*v.x + v.y*v.y + v.z*v.z + v.w*v.w;
        for (int off = 32; off; off >>= 1) {
            s  += __shfl_xor(s,  off);
            sq += __shfl_xor(sq, off);
        }
        float mean = s * (1.0f / D_MODEL);
        float var  = sq * (1.0f / D_MODEL) - mean * mean;
        float inv  = rsqrtf(var + 1e-6f);
        float4 g = ((const float4*)gamma)[lane];
        float4 bb = ((const float4*)beta)[lane];
        bf16x4 o;
        o[0] = f2bf((v.x - mean) * inv * g.x + bb.x);
        o[1] = f2bf((v.y - mean) * inv * g.y + bb.y);
        o[2] = f2bf((v.z - mean) * inv * g.z + bb.z);
        o[3] = f2bf((v.w - mean) * inv * g.w + bb.w);
        *(bf16x4*)(x_ln + (size_t)row * D_MODEL + lane * 4) = o;
        return;
    }
    if (b < 64) {
        int v = b >> 3, sl = b & 7, h = v & 3;
        const float* att = ((v < 4) ? att_src : att_dst) + h * C_CH;
        float acc = 0.f;
        #pragma unroll
        for (int j = 0; j < 32; ++j) {
            int c = sl * 32 + j;
            acc = fmaf(Wg[(size_t)(h * 256 + c) * 256 + tid], att[c], acc);
        }
        atomicAdd(&t[v * 256 + tid], acc);
        return;
    }
    if (b < 1088) {
        // V partial over one 64-wide c-slice, written to Vp[cs]
        int bb2 = b - 64;
        int orig = bb2 >> 2, cs = bb2 & 3;
        int og = (orig & 63) * 4, h = orig >> 6;
        const float* w2r = W2 + (size_t)og * 256;
        const float* wgp = Wg + ((size_t)h * 256) * 256 + tid;
        float a0 = 0.f, a1 = 0.f, a2 = 0.f, a3 = 0.f;
        int cb = cs * 64;
        #pragma unroll 4
        for (int c = cb; c < cb + 64; ++c) {
            float wv = wgp[(size_t)c * 256];
            a0 = fmaf(w2r[c],       wv, a0);
            a1 = fmaf(w2r[256 + c], wv, a1);
            a2 = fmaf(w2r[512 + c], wv, a2);
            a3 = fmaf(w2r[768 + c], wv, a3);
        }
        size_t base = (size_t)cs * PSZ + (size_t)og * 1024 + h * 256 + tid;
        Vp[base]        = a0;
        Vp[base + 1024] = a1;
        Vp[base + 2048] = a2;
        Vp[base + 3072] = a3;
        return;
    }
    {
        // padded-CSR scatter
        int e = (b - 1088) * 256 + tid;
        int src, dst;
        if (e < E_EDGES) { src = ei[e]; dst = ei[E_EDGES + e]; }
        else             { src = dst = e - E_EDGES; }
        int pos = atomicAdd(cnt + dst, 1);
        csr[(size_t)dst * MAXDEG + pos] = src;
    }
}

// ==== K2: 0..1023 Wz split-4 -> Wzp (plain stores; V summed from Vp via LDS) |
//          1024..1087 u2/c0 ====
__global__ __launch_bounds__(256) void prep2(
    const float* __restrict__ t, const float* __restrict__ W1,
    const float* __restrict__ b1, const float* __restrict__ Vp,
    const float* __restrict__ W2, const float* __restrict__ bg,
    const float* __restrict__ b2, float* __restrict__ u2,
    float* __restrict__ c0, float* __restrict__ Wzp,
    float* __restrict__ bias_z)
{
    __shared__ float red[4][4];
    __shared__ float vsh[4][64];
    int b = blockIdx.x;
    int d = threadIdx.x;

    if (b < 1024) {
        int orig = b >> 2, ks = b & 3;
        int og = (orig & 63) * 4, h = orig >> 6;
        int lane = d & 63, wid = d >> 6;
        int kb = ks * 64;
        size_t vbase = (size_t)og * 1024 + h * 256;

        // cooperative sum of the 4 V-partials for this block's 4x64 slice
        {
            int j = d >> 6, kk = d & 63;
            float s = 0.f;
            #pragma unroll
            for (int cs = 0; cs < 4; ++cs)
                s += Vp[(size_t)cs * PSZ + vbase + (size_t)j * 1024 + kb + kk];
            vsh[j][kk] = s;
        }
        __syncthreads();

        float a0 = 0.f, a1 = 0.f, a2 = 0.f, a3 = 0.f;
        #pragma unroll 4
        for (int k = 0; k < 64; ++k) {
            float w1v = W1[(size_t)(kb + k) * 256 + d];
            a0 = fmaf(vsh[0][k], w1v, a0);
            a1 = fmaf(vsh[1][k], w1v, a1);
            a2 = fmaf(vsh[2][k], w1v, a2);
            a3 = fmaf(vsh[3][k], w1v, a3);
        }
        size_t base = (size_t)ks * PSZ + vbase + d;
        Wzp[base]        = a0;
        Wzp[base + 1024] = a1;
        Wzp[base + 2048] = a2;
        Wzp[base + 3072] = a3;

        if (ks == 0) {
            float b1v = b1[d];
            #pragma unroll
            for (int j = 0; j < 4; ++j) {
                float vsum = 0.f;
                #pragma unroll
                for (int cs = 0; cs < 4; ++cs)
                    vsum += Vp[(size_t)cs * PSZ + vbase + (size_t)j * 1024 + d];
                float p = vsum * b1v;
                for (int s = 32; s; s >>= 1) p += __shfl_xor(p, s);
                if (lane == 0) red[j][wid] = p;
            }
            __syncthreads();
            if (d < 4) {
                float s = red[d][0] + red[d][1] + red[d][2] + red[d][3];
                atomicAdd(&bias_z[og + d], 0.25f * s);
            }
            if (h == 0) {
                __syncthreads();
                float bgv = bg[d];
                #pragma unroll
                for (int j = 0; j < 4; ++j) {
                    float q = W2[(size_t)(og + j) * 256 + d] * bgv;
                    for (int s = 32; s; s >>= 1) q += __shfl_xor(q, s);
                    if (lane == 0) red[j][wid] = q;
                }
                __syncthreads();
                if (d < 4) {
                    float s = red[d][0] + red[d][1] + red[d][2] + red[d][3];
                    atomicAdd(&bias_z[og + d], s + b2[og + d]);
                }
            }
        }
        return;
    }
    {
        int bb = b - 1024;
        int v = bb >> 3, sl = bb & 7;
        const float* tv = t + v * 256;
        float acc = 0.f;
        #pragma unroll
        for (int j = 0; j < 32; ++j) {
            int k = sl * 32 + j;
            acc = fmaf(tv[k], W1[(size_t)k * 256 + d], acc);
        }
        atomicAdd(&u2[v * 256 + d], acc);
        if (d < 32) {
            float p = tv[sl * 32 + d] * b1[sl * 32 + d];
            for (int s = 16; s; s >>= 1) p += __shfl_xor(p, s);
            if (d == 0) atomicAdd(&c0[v], p);
        }
    }
}

// ==== K3: 0..4095 logits | 4096..4351 Wzp sum + f32->bf16 cvt ====
__global__ __launch_bounds__(256) void logits_cvt(
    const __bf16* __restrict__ x_ln, const float* __restrict__ u2,
    const float* __restrict__ c0, float* __restrict__ a_src,
    float* __restrict__ a_dst, const float* __restrict__ Wzp,
    __bf16* __restrict__ Wz)
{
    int b = blockIdx.x;
    int tid = threadIdx.x;
    if (b >= 4096) {
        int idx = (b - 4096) * 256 + tid;    // 65536 float4 groups
        float4 v = make_float4(0.f, 0.f, 0.f, 0.f);
        #pragma unroll
        for (int p = 0; p < 4; ++p) {
            float4 t4 = ((const float4*)(Wzp + (size_t)p * PSZ))[idx];
            v.x += t4.x; v.y += t4.y; v.z += t4.z; v.w += t4.w;
        }
        bf16x4 o;
        o[0] = f2bf(v.x); o[1] = f2bf(v.y); o[2] = f2bf(v.z); o[3] = f2bf(v.w);
        *(bf16x4*)(Wz + (size_t)idx * 4) = o;
        return;
    }
    __shared__ float u2s[8][256];
    __shared__ float c0s[8];
    #pragma unroll
    for (int k = 0; k < 8; ++k) u2s[k][tid] = u2[k * 256 + tid];
    if (tid < 8) c0s[tid] = c0[tid];
    __syncthreads();

    int wave = tid >> 6, lane = tid & 63;
    int n = b * 4 + wave;
    int v = lane >> 3, p = lane & 7;
    const __bf16* xp = x_ln + (size_t)n * D_MODEL + p * 32;
    const float*  up = &u2s[v][p * 32];
    float acc = 0.f;
    #pragma unroll
    for (int ti = 0; ti < 4; ++ti) {
        bf16x8 x = *(const bf16x8*)(xp + ti * 8);
        #pragma unroll
        for (int j = 0; j < 8; ++j)
            acc = fmaf(bf2f(x[j]), up[ti * 8 + j], acc);
    }
    acc += __shfl_xor(acc, 1);
    acc += __shfl_xor(acc, 2);
    acc += __shfl_xor(acc, 4);
    if (p == 0) {
        float o = acc + c0s[v];
        if (v < 4) a_src[n * H_HEADS + v] = o;
        else       a_dst[n * H_HEADS + (v - 4)] = o;
    }
}

// ==== K4: fused GAT aggregation + output projection ====
// Block = 64 dst nodes = one gemm A-panel; 512 threads / 8 waves; grid = 256
// blocks = exactly 1/CU. Kills the agg[N,1024] global round-trip (64 MB HBM).
// Phase 1 (lane-parallel, the r9-verified form): wave w aggregates nodes
// w*8..w*8+7. Per node: one parallel a_src burst (lane = edge), wave-reduce
// softmax denom, weights broadcast via __shfl (no LDS table -> no cross-node
// LDS dependency, gather bursts of consecutive nodes can overlap), x_ln rows
// gathered in 8-wide independent bursts; normalized bf16 row -> T in LDS.
// Phase 2: proven gemm fragment pattern, A from LDS T (stride 2064 B: 4-dw
// bank class, 2-way aliasing = free), B = Wz streamed from L2 (512 KB/block).
#define TPAD 1032

__global__ __launch_bounds__(512, 1) void gat_gemm(
    const __bf16* __restrict__ x_ln, const float* __restrict__ a_src,
    const float* __restrict__ a_dst, const int* __restrict__ cnt,
    const int* __restrict__ csr, const __bf16* __restrict__ Wz,
    const float* __restrict__ bias_z, const float* __restrict__ resid,
    float* __restrict__ outf)
{
    __shared__ __align__(16) __bf16 T[64 * TPAD];
    int tid = threadIdx.x;
    int lane = tid & 63, w = tid >> 6;
    int m0 = blockIdx.x * 64;

    // ---------------- phase 1: aggregate 8 nodes per wave ----------------
    #pragma unroll 2
    for (int nn = 0; nn < 8; ++nn) {
        int node = w * 8 + nn;
        int i = m0 + node;
        int deg = cnt[i];
        int sidx = csr[(size_t)i * MAXDEG + lane];   // coalesced; garbage past deg
        float4 ad = *(const float4*)(a_dst + i * H_HEADS);

        float4 wgt = make_float4(0.f, 0.f, 0.f, 0.f);
        if (lane < deg) {
            float4 as = *(const float4*)(a_src + sidx * H_HEADS);
            float l0 = as.x + ad.x, l1 = as.y + ad.y,
                  l2 = as.z + ad.z, l3 = as.w + ad.w;
            l0 = (l0 > 0.f) ? l0 : 0.2f * l0;
            l1 = (l1 > 0.f) ? l1 : 0.2f * l1;
            l2 = (l2 > 0.f) ? l2 : 0.2f * l2;
            l3 = (l3 > 0.f) ? l3 : 0.2f * l3;
            wgt = make_float4(__expf(l0), __expf(l1), __expf(l2), __expf(l3));
        }
        float s0 = wgt.x, s1 = wgt.y, s2 = wgt.z, s3 = wgt.w;
        #pragma unroll
        for (int off = 32; off; off >>= 1) {
            s0 += __shfl_xor(s0, off);
            s1 += __shfl_xor(s1, off);
            s2 += __shfl_xor(s2, off);
            s3 += __shfl_xor(s3, off);
        }

        float acc[4][4] = {};
        for (int e0 = 0; e0 < deg; e0 += 8) {
            bf16x4 X[8];
            float4 W[8];
            #pragma unroll
            for (int j = 0; j < 8; ++j) {
                int ee = e0 + j;
                bool val = ee < deg;
                int el = val ? ee : 0;
                int s = __shfl(sidx, el);
                X[j] = *(const bf16x4*)(x_ln + (size_t)s * D_MODEL + lane * 4);
                float4 wv;
                wv.x = __shfl(wgt.x, el);
                wv.y = __shfl(wgt.y, el);
                wv.z = __shfl(wgt.z, el);
                wv.w = __shfl(wgt.w, el);
                W[j] = val ? wv : make_float4(0.f, 0.f, 0.f, 0.f);
            }
            #pragma unroll
            for (int j = 0; j < 8; ++j) {
                #pragma unroll
                for (int d = 0; d < 4; ++d) {
                    float xv = bf2f(X[j][d]);
                    acc[0][d] = fmaf(W[j].x, xv, acc[0][d]);
                    acc[1][d] = fmaf(W[j].y, xv, acc[1][d]);
                    acc[2][d] = fmaf(W[j].z, xv, acc[2][d]);
                    acc[3][d] = fmaf(W[j].w, xv, acc[3][d]);
                }
            }
        }
        float sc[4] = {0.25f / s0, 0.25f / s1, 0.25f / s2, 0.25f / s3};
        #pragma unroll
        for (int h = 0; h < 4; ++h) {
            bf16x4 o;
            #pragma unroll
            for (int j = 0; j < 4; ++j) o[j] = f2bf(acc[h][j] * sc[h]);
            *(bf16x4*)(T + node * TPAD + h * 256 + lane * 4) = o;
        }
    }
    __syncthreads();

    // ---------------- phase 2: project T[64,1024] @ Wz^T ----------------
    int quad = lane >> 4, l16 = lane & 15;
    int n0 = w * 32;
    f32x4 pacc[4][2] = {};
    #pragma unroll 4
    for (int kk = 0; kk < HC; kk += 32) {
        bf16x8 af[4], bfr[2];
        #pragma unroll
        for (int mt = 0; mt < 4; ++mt)
            af[mt] = *(const bf16x8*)(T + (mt * 16 + l16) * TPAD
                                      + kk + quad * 8);
        #pragma unroll
        for (int nt = 0; nt < 2; ++nt)
            bfr[nt] = *(const bf16x8*)(Wz + (size_t)(n0 + nt * 16 + l16) * HC
                                       + kk + quad * 8);
        #pragma unroll
        for (int mt = 0; mt < 4; ++mt)
            #pragma unroll
            for (int nt = 0; nt < 2; ++nt)
                pacc[mt][nt] = __builtin_amdgcn_mfma_f32_16x16x32_bf16(
                    af[mt], bfr[nt], pacc[mt][nt], 0, 0, 0);
    }

    #pragma unroll
    for (int nt = 0; nt < 2; ++nt) {
        int col = n0 + nt * 16 + l16;
        float bv = bias_z[col];
        #pragma unroll
        for (int mt = 0; mt < 4; ++mt) {
            int row = m0 + mt * 16 + quad * 4;
            #pragma unroll
            for (int r = 0; r < 4; ++r) {
                size_t off = (size_t)(row + r) * C_CH + col;
                outf[off] = pacc[mt][nt][r] + bv + resid[off];
            }
        }
    }
}

extern "C" void kernel_launch(void* const* d_in, const int* in_sizes, int n_in,
                              void* d_out, int out_size, void* d_ws, size_t ws_size,
                              hipStream_t stream)
{
    const float* inp      = (const float*)d_in[0];
    const int*   ei       = (const int*)  d_in[1];
    const float* ln_gamma = (const float*)d_in[2];
    const float* ln_beta  = (const float*)d_in[3];
    const float* W1       = (const float*)d_in[4];
    const float* b1       = (const float*)d_in[5];
    const float* W_gat    = (const float*)d_in[6];
    const float* att_src  = (const float*)d_in[7];
    const float* att_dst  = (const float*)d_in[8];
    const float* bias_gat = (const float*)d_in[9];
    const float* W2       = (const float*)d_in[10];
    const float* b2       = (const float*)d_in[11];

    char* ws = (char*)d_ws;
    __bf16* x_ln_bf = (__bf16*)(ws);                         //  8 MB
    __bf16* Wz_b    = (__bf16*)(ws + (40ull << 20));         // 512 KB
    float*  a_src_b = (float*)(ws + (41ull << 20));          // 256 KB
    float*  a_dst_b = a_src_b + (size_t)N_NODES * H_HEADS;   // 256 KB
    // ---- zero region start (42 MB) ----
    float*  t_vec   = (float*)(ws + (42ull << 20));          //  8 KB
    float*  u2      = t_vec + 2048;                          //  8 KB
    float*  c0      = u2 + 2048;                             //  32 B
    float*  bias_z  = c0 + 8;                                //  1 KB
    int*    cnt     = (int*)(bias_z + 256);                  // 64 KB
    // ---- zero region end ----
    int*    csr     = (int*)(ws + (45ull << 20));            //  4 MB
    float*  Vp      = (float*)(ws + (49ull << 20));          //  4 MB (4 partials)
    float*  Wzp     = (float*)(ws + (57ull << 20));          //  4 MB (4 partials)

    size_t zbytes = (2048 + 2048 + 8 + 256) * sizeof(float)
                  + N_NODES * sizeof(int);
    hipMemsetAsync(t_vec, 0, zbytes, stream);

    prep1_ln<<<1408 + 4096, 256, 0, stream>>>(W_gat, att_src, att_dst, W2, ei,
                                              inp, ln_gamma, ln_beta,
                                              t_vec, Vp, cnt, csr, x_ln_bf);
    prep2<<<1088, 256, 0, stream>>>(t_vec, W1, b1, Vp, W2, bias_gat, b2,
                                    u2, c0, Wzp, bias_z);
    logits_cvt<<<4096 + 256, 256, 0, stream>>>(x_ln_bf, u2, c0,
                                               a_src_b, a_dst_b, Wzp, Wz_b);
    gat_gemm<<<N_NODES / 64, 512, 0, stream>>>(x_ln_bf, a_src_b, a_dst_b,
                                               cnt, csr, Wz_b, bias_z,
                                               inp, (float*)d_out);
}